// Round 1
// baseline (18756.761 us; speedup 1.0000x reference)
//
#include <hip/hip_runtime.h>
#include <math.h>

#define B 512
#define S 64
#define T 32
#define E 512
#define H 1024
#define VOUTD 128
#define H2 (2*H)
#define H3 (3*H)
#define H6 (6*H)

__device__ __forceinline__ float sigmoidf_(float x) { return 1.0f / (1.0f + expf(-x)); }

// ---------------------------------------------------------------------------
// Generic fp32 GEMM: C[M,N] = A @ W^T + bias, W is N x K row-major.
// Optional row gather: if idx != nullptr, row m of A is Abase + idx[m*idxStride+idxOff]*lda.
// Tiles: 64x64x16, 256 threads, 4x4 microtile. All dims divide evenly here.
// ---------------------------------------------------------------------------
__global__ __launch_bounds__(256) void gemm_bias(
    const float* __restrict__ Abase,
    const int* __restrict__ idx, int idxStride, int idxOff, int lda,
    const float* __restrict__ W,
    const float* __restrict__ bias,
    float* __restrict__ C, int N, int K)
{
    __shared__ float As[16][68];   // [k][m], +4 pad keeps float4 alignment, 2-way-max bank alias (free)
    __shared__ float Ws[16][68];   // [k][n]
    const int t  = threadIdx.x;
    const int m0 = blockIdx.y * 64;
    const int n0 = blockIdx.x * 64;

    const int lr = t >> 2;          // 0..63 tile row for loading
    const int lc = (t & 3) << 2;    // 0,4,8,12 k-offset (float4)

    const int tx = t & 15, ty = t >> 4;
    const int tn0 = tx << 2, tm0 = ty << 2;

    const int arow = m0 + lr;
    const float* Aptr = idx ? (Abase + (size_t)idx[arow * idxStride + idxOff] * lda)
                            : (Abase + (size_t)arow * lda);
    const float* Wptr = W + (size_t)(n0 + lr) * K;

    float acc[4][4] = {{0.f}};

    for (int k0 = 0; k0 < K; k0 += 16) {
        float4 a4 = *(const float4*)(Aptr + k0 + lc);
        float4 w4 = *(const float4*)(Wptr + k0 + lc);
        __syncthreads();
        As[lc+0][lr] = a4.x; As[lc+1][lr] = a4.y; As[lc+2][lr] = a4.z; As[lc+3][lr] = a4.w;
        Ws[lc+0][lr] = w4.x; Ws[lc+1][lr] = w4.y; Ws[lc+2][lr] = w4.z; Ws[lc+3][lr] = w4.w;
        __syncthreads();
#pragma unroll
        for (int kk = 0; kk < 16; ++kk) {
            float4 av = *(const float4*)&As[kk][tm0];
            float4 wv = *(const float4*)&Ws[kk][tn0];
            float am[4] = {av.x, av.y, av.z, av.w};
            float wn[4] = {wv.x, wv.y, wv.z, wv.w};
#pragma unroll
            for (int i = 0; i < 4; ++i)
#pragma unroll
                for (int j = 0; j < 4; ++j)
                    acc[i][j] += am[i] * wn[j];
        }
    }

    const float b0 = bias[n0+tn0+0], b1 = bias[n0+tn0+1];
    const float b2 = bias[n0+tn0+2], b3 = bias[n0+tn0+3];
#pragma unroll
    for (int i = 0; i < 4; ++i) {
        float4 o = make_float4(acc[i][0]+b0, acc[i][1]+b1, acc[i][2]+b2, acc[i][3]+b3);
        *(float4*)(C + (size_t)(m0 + tm0 + i) * N + n0 + tn0) = o;
    }
}

// ---------------------------------------------------------------------------
// Encoder GEMM: fwd+bwd fused. Rows 0..511 = forward dir, 512..1023 = backward.
// Gather mode (srcIdx != nullptr): A row r -> enc_emb[src[r%512, s or S-1-s]].
// Plain mode: A = hE (1024 x lda, fwd rows then bwd rows).
// Weight/bias set selected per 64-row tile (512 is tile-aligned).
// ---------------------------------------------------------------------------
__global__ __launch_bounds__(256) void gemm_enc(
    const float* __restrict__ Abase, int lda, int K,
    const int* __restrict__ srcIdx, int s,
    const float* __restrict__ W1, const float* __restrict__ bias1,
    const float* __restrict__ W2, const float* __restrict__ bias2,
    float* __restrict__ C, int N)
{
    __shared__ float As[16][68];
    __shared__ float Ws[16][68];
    const int t  = threadIdx.x;
    const int m0 = blockIdx.y * 64;
    const int n0 = blockIdx.x * 64;
    const bool bwd = (m0 >= B);
    const float* W    = bwd ? W2 : W1;
    const float* bias = bwd ? bias2 : bias1;

    const int lr = t >> 2;
    const int lc = (t & 3) << 2;
    const int tx = t & 15, ty = t >> 4;
    const int tn0 = tx << 2, tm0 = ty << 2;

    const int arow = m0 + lr;
    const float* Aptr;
    if (srcIdx) {
        int r = arow & (B - 1);
        int sidx = bwd ? (S - 1 - s) : s;
        Aptr = Abase + (size_t)srcIdx[r * S + sidx] * lda;
    } else {
        Aptr = Abase + (size_t)arow * lda;
    }
    const float* Wptr = W + (size_t)(n0 + lr) * K;

    float acc[4][4] = {{0.f}};

    for (int k0 = 0; k0 < K; k0 += 16) {
        float4 a4 = *(const float4*)(Aptr + k0 + lc);
        float4 w4 = *(const float4*)(Wptr + k0 + lc);
        __syncthreads();
        As[lc+0][lr] = a4.x; As[lc+1][lr] = a4.y; As[lc+2][lr] = a4.z; As[lc+3][lr] = a4.w;
        Ws[lc+0][lr] = w4.x; Ws[lc+1][lr] = w4.y; Ws[lc+2][lr] = w4.z; Ws[lc+3][lr] = w4.w;
        __syncthreads();
#pragma unroll
        for (int kk = 0; kk < 16; ++kk) {
            float4 av = *(const float4*)&As[kk][tm0];
            float4 wv = *(const float4*)&Ws[kk][tn0];
            float am[4] = {av.x, av.y, av.z, av.w};
            float wn[4] = {wv.x, wv.y, wv.z, wv.w};
#pragma unroll
            for (int i = 0; i < 4; ++i)
#pragma unroll
                for (int j = 0; j < 4; ++j)
                    acc[i][j] += am[i] * wn[j];
        }
    }

    const float b0 = bias[n0+tn0+0], b1 = bias[n0+tn0+1];
    const float b2 = bias[n0+tn0+2], b3 = bias[n0+tn0+3];
#pragma unroll
    for (int i = 0; i < 4; ++i) {
        float4 o = make_float4(acc[i][0]+b0, acc[i][1]+b1, acc[i][2]+b2, acc[i][3]+b3);
        *(float4*)(C + (size_t)(m0 + tm0 + i) * N + n0 + tn0) = o;
    }
}

// ---------------------------------------------------------------------------
// GRU gate: h = (1-z)*n + z*h, in place. Works over any leading row count via grid.
// gi/gh rows have stride 3*Hd. Element i covers (row, j) = (i/Hd, i%Hd).
// ---------------------------------------------------------------------------
__global__ __launch_bounds__(256) void gru_gate(
    const float* __restrict__ gi, const float* __restrict__ gh,
    float* __restrict__ h, int Hd)
{
    int i = blockIdx.x * blockDim.x + threadIdx.x;
    int b = i / Hd, j = i - b * Hd;
    const float* gib = gi + (size_t)b * 3 * Hd;
    const float* ghb = gh + (size_t)b * 3 * Hd;
    float r = sigmoidf_(gib[j] + ghb[j]);
    float z = sigmoidf_(gib[Hd + j] + ghb[Hd + j]);
    float n = tanhf(gib[2 * Hd + j] + r * ghb[2 * Hd + j]);
    h[i] = (1.0f - z) * n + z * h[i];
}

__global__ void zero_kernel(float* __restrict__ p, int n)
{
    int i = blockIdx.x * blockDim.x + threadIdx.x;
    if (i < n) p[i] = 0.0f;
}

// hh[b, 0:H] = h_f[b], hh[b, H:2H] = h_b[b]; tok[b] = tgt[b,0]
__global__ __launch_bounds__(256) void init_hh_tok(
    const float* __restrict__ h_f, const float* __restrict__ h_b,
    const int* __restrict__ tgt, float* __restrict__ hh, int* __restrict__ tok)
{
    int i = blockIdx.x * blockDim.x + threadIdx.x;   // over B*2H
    int b = i >> 11;          // / 2048
    int j = i & 2047;
    hh[i] = (j < H) ? h_f[(size_t)b * H + j] : h_b[(size_t)b * H + (j - H)];
    if (j == 0) tok[b] = tgt[b * T];
}

// ---------------------------------------------------------------------------
// logits = hh @ W_fc^T + b_fc  (V=128), write to out[b,t,:], tok[b] = argmax
// (first-index tie-break = jnp.argmax semantics). One block per batch row.
// ---------------------------------------------------------------------------
__global__ __launch_bounds__(128) void logits_argmax(
    const float* __restrict__ hh, const float* __restrict__ W_fc,
    const float* __restrict__ b_fc, float* __restrict__ out,
    int* __restrict__ tok, int t)
{
    __shared__ float sh[H2];
    __shared__ float svals[128];
    __shared__ int   sidx[128];
    const int b = blockIdx.x;
    const int v = threadIdx.x;
    const float* hrow = hh + (size_t)b * H2;
    for (int i = v; i < H2 / 4; i += 128)
        ((float4*)sh)[i] = ((const float4*)hrow)[i];
    __syncthreads();
    const float* wrow = W_fc + (size_t)v * H2;
    float acc = b_fc[v];
    for (int k = 0; k < H2; k += 4) {
        float4 w4 = *(const float4*)(wrow + k);
        float4 h4 = *(const float4*)(sh + k);
        acc += w4.x * h4.x + w4.y * h4.y + w4.z * h4.z + w4.w * h4.w;
    }
    out[(size_t)b * ((T - 1) * VOUTD) + (size_t)t * VOUTD + v] = acc;

    svals[v] = acc; sidx[v] = v;
    __syncthreads();
    for (int off = 64; off > 0; off >>= 1) {
        if (v < off) {
            float ov = svals[v + off]; int oi = sidx[v + off];
            if (ov > svals[v] || (ov == svals[v] && oi < sidx[v])) {
                svals[v] = ov; sidx[v] = oi;
            }
        }
        __syncthreads();
    }
    if (v == 0) tok[b] = sidx[0];
}

// ---------------------------------------------------------------------------
extern "C" void kernel_launch(void* const* d_in, const int* in_sizes, int n_in,
                              void* d_out, int out_size, void* d_ws, size_t ws_size,
                              hipStream_t stream)
{
    const int*   src     = (const int*)d_in[0];
    const int*   tgt     = (const int*)d_in[1];
    const float* enc_emb = (const float*)d_in[2];
    const float* dec_emb = (const float*)d_in[3];
    const float* W_ih_f  = (const float*)d_in[4];
    const float* W_hh_f  = (const float*)d_in[5];
    const float* b_ih_f  = (const float*)d_in[6];
    const float* b_hh_f  = (const float*)d_in[7];
    const float* W_ih_b  = (const float*)d_in[8];
    const float* W_hh_b  = (const float*)d_in[9];
    const float* b_ih_b  = (const float*)d_in[10];
    const float* b_hh_b  = (const float*)d_in[11];
    const float* W_ih_d  = (const float*)d_in[12];
    const float* W_hh_d  = (const float*)d_in[13];
    const float* b_ih_d  = (const float*)d_in[14];
    const float* b_hh_d  = (const float*)d_in[15];
    const float* W_fc    = (const float*)d_in[16];
    const float* b_fc    = (const float*)d_in[17];
    float* out = (float*)d_out;

    // Workspace layout (fp32): ~32 MB
    float* hE  = (float*)d_ws;                 // (2B) x H : fwd rows 0..511, bwd rows 512..1023
    float* hh  = hE  + (size_t)2 * B * H;      // B x 2H
    float* giE = hh  + (size_t)B * H2;         // (2B) x 3H (encoder) / B x 6H (decoder)
    float* ghE = giE + (size_t)2 * B * H3;     // (2B) x 3H (encoder) / B x 6H (decoder)
    int*   tok = (int*)(ghE + (size_t)2 * B * H3);  // B

    const float* h_f = hE;
    const float* h_b = hE + (size_t)B * H;

    dim3 blk(256);

    // h0 = 0 for both directions (ws is poisoned 0xAA before every call)
    zero_kernel<<<dim3((2 * B * H) / 256), blk, 0, stream>>>(hE, 2 * B * H);

    // ---------------- Encoder: 64 steps, fwd+bwd fused ----------------
    dim3 grid_gi(H3 / 64, (2 * B) / 64);   // 48 x 16
    dim3 grid_gh(H3 / 64, (2 * B) / 64);
    dim3 grid_gate((2 * B * H) / 256);
    for (int s = 0; s < S; ++s) {
        gemm_enc<<<grid_gi, blk, 0, stream>>>(enc_emb, E, E, src, s,
                                              W_ih_f, b_ih_f, W_ih_b, b_ih_b, giE, H3);
        gemm_enc<<<grid_gh, blk, 0, stream>>>(hE, H, H, nullptr, 0,
                                              W_hh_f, b_hh_f, W_hh_b, b_hh_b, ghE, H3);
        gru_gate<<<grid_gate, blk, 0, stream>>>(giE, ghE, hE, H);
    }

    // hh = [h_f, h_b]; tok = tgt[:,0]
    init_hh_tok<<<dim3((B * H2) / 256), blk, 0, stream>>>(h_f, h_b, tgt, hh, tok);

    // ---------------- Decoder: 31 steps with argmax feedback ----------------
    dim3 grid_d(H6 / 64, B / 64);          // 96 x 8
    dim3 grid_dgate((B * H2) / 256);
    for (int t = 0; t < T - 1; ++t) {
        gemm_bias<<<grid_d, blk, 0, stream>>>(dec_emb, tok, 1, 0, E,
                                              W_ih_d, b_ih_d, giE, H6, E);
        gemm_bias<<<grid_d, blk, 0, stream>>>(hh, nullptr, 0, 0, H2,
                                              W_hh_d, b_hh_d, ghE, H6, H2);
        gru_gate<<<grid_dgate, blk, 0, stream>>>(giE, ghE, hh, H2);
        logits_argmax<<<dim3(B), dim3(128), 0, stream>>>(hh, W_fc, b_fc, out, tok, t);
    }
}